// Round 10
// baseline (538.407 us; speedup 1.0000x reference)
//
#include <hip/hip_runtime.h>
#include <hip/hip_bf16.h>

typedef unsigned short u16;
typedef __bf16 bf16x8 __attribute__((ext_vector_type(8)));
typedef float f32x4 __attribute__((ext_vector_type(4)));

#define S_DIM 2048
#define B_DIM 32
#define H_DIM 1024
#define M_DIM (S_DIM * B_DIM)
#define NKS 32          // K = 1024 in 32 steps of 32
#define NSLICE 8        // N = 1024 in 8 slices of 128 cols

__device__ __forceinline__ float fast_tanh(float x) {
  // tanh(x) = 1 - 2/(e^{2x}+1); e->inf => 1, e->0 => -1; no NaN
  float e = __expf(2.0f * x);
  return 1.0f - 2.0f * __builtin_amdgcn_rcpf(e + 1.0f);
}

__device__ __forceinline__ void gload_lds16(const void* g, void* l) {
  __builtin_amdgcn_global_load_lds(
      (const __attribute__((address_space(1))) unsigned int*)g,
      (__attribute__((address_space(3))) unsigned int*)l,
      16, 0, 0);
}

// Convert W_attn[:, H:2H] (f32, row stride 2H) -> W2 bf16 [H][H] row-major
__global__ void wconv_kernel(const float* __restrict__ W, u16* __restrict__ W2) {
  const int h = blockIdx.x;
  const int t = threadIdx.x;
  float4 w4 = *(const float4*)(W + (size_t)h * (2 * H_DIM) + H_DIM + t * 4);
  union { u16 s[4]; uint2 v; } pk;
  pk.s[0] = __builtin_bit_cast(u16, (__bf16)w4.x);
  pk.s[1] = __builtin_bit_cast(u16, (__bf16)w4.y);
  pk.s[2] = __builtin_bit_cast(u16, (__bf16)w4.z);
  pk.s[3] = __builtin_bit_cast(u16, (__bf16)w4.w);
  *(uint2*)(W2 + (size_t)h * H_DIM + t * 4) = pk.v;
}

// u_t[h][b] = dot(hidden[b,:], W_attn[h, 0:H]) + b_attn[h]   (fp32, transposed)
__global__ void uprep_kernel(const float* __restrict__ hidden, const float* __restrict__ W,
                             const float* __restrict__ bias, float* __restrict__ u_t) {
  int t = blockIdx.x * 256 + threadIdx.x;   // 0..131071
  int h = t >> 7;
  int b = (t >> 2) & 31;
  int kq = t & 3;
  const float4* hv = (const float4*)(hidden + (size_t)b * H_DIM) + kq * 64;
  const float4* wv = (const float4*)(W + (size_t)h * (2 * H_DIM)) + kq * 64;
  float acc = 0.f;
  #pragma unroll 4
  for (int i = 0; i < 64; ++i) {
    float4 a = hv[i], w = wv[i];
    acc += a.x * w.x + a.y * w.y + a.z * w.z + a.w * w.w;
  }
  acc += __shfl_xor(acc, 1);
  acc += __shfl_xor(acc, 2);
  if (kq == 0) u_t[(size_t)h * B_DIM + b] = acc + bias[h];
}

// Fused GEMM + tanh + v-dot. 128x128 tile, BK=32, 256 thr / 4 waves (2x2),
// wave tile 64x64, acc[4][4] f32x4 = 64 AGPR.
// 3-deep LDS page pipeline, counted vmcnt (NEVER 0 in the loop), raw s_barrier:
//   iter ks: stage pages for ks+2 (B 2 glds, A 4 glds, all global_load_lds,
//   A staged as f32 - no reg round-trip), read frags from page ks%3
//   (A f32->bf16 cvt at read), 16 MFMA, s_waitcnt vmcnt(6) [drains pages ks+1,
//   issued one full iteration ago], s_barrier.
// LDS kq-major pages: linear gload dest, 16-lane-contiguous ds reads
// (R4/R7-measured 0 conflicts). XCD-bijective swizzle: 8 n-siblings of each
// m-panel share an XCD (R6: FETCH 1.06GB -> 180MB).
__global__ __launch_bounds__(256, 2)
void gemm_kernel(const float* __restrict__ enc, const u16* __restrict__ W2,
                 const float* __restrict__ u_t, const float* __restrict__ v,
                 float* __restrict__ partial) {
  __shared__ float A_s[3][4096];   // page: [k4 0..7][row 0..127] x 4 floats = 16 KB
  __shared__ u16   B_s[3][4096];   // page: [kq8 0..3][col 0..127] x 8 bf16 = 8 KB
  __shared__ float red_s[2][128];

  const int tid  = threadIdx.x;
  const int lane = tid & 63;
  const int wid  = tid >> 6;    // 0..3
  const int wm   = wid >> 1;    // 0..1
  const int wn   = wid & 1;     // 0..1
  const int q    = lane >> 4;   // 0..3
  const int c16  = lane & 15;

  // XCD-bijective decode (4096 blocks): xcd = blockIdx%8 == m-panel id.
  const int bidx = blockIdx.x;
  const int ns   = (bidx >> 3) & 7;
  const int mt   = (bidx & 7) + 8 * (bidx >> 6);
  const int m0   = mt * 128;
  const int n0   = ns * 128;

  f32x4 acc[4][4];
  #pragma unroll
  for (int mi = 0; mi < 4; ++mi)
    #pragma unroll
    for (int nf = 0; nf < 4; ++nf) {
      f32x4 z = {0.f, 0.f, 0.f, 0.f};
      acc[mi][nf] = z;
    }

  // stage pages for k-tile kt: B first (older in vmcnt FIFO), then A.
  #define STAGE(pg, kt)                                                       \
    {                                                                         \
      _Pragma("unroll")                                                       \
      for (int j = 0; j < 2; ++j) {                                           \
        const int slot = j * 256 + tid;                                       \
        gload_lds16(W2 + (size_t)(n0 + (slot & 127)) * H_DIM + (kt) * 32 +    \
                        (slot >> 7) * 8,                                      \
                    &B_s[pg][slot * 8]);                                      \
      }                                                                       \
      _Pragma("unroll")                                                       \
      for (int j = 0; j < 4; ++j) {                                           \
        const int slot = j * 256 + tid;                                       \
        gload_lds16(enc + (size_t)(m0 + (slot & 127)) * H_DIM + (kt) * 32 +   \
                        (slot >> 7) * 4,                                      \
                    &A_s[pg][slot * 4]);                                      \
      }                                                                       \
    }

  // ---- prologue: stage pages 0,1; drain page 0 only (vmcnt(6)) ----
  STAGE(0, 0);
  STAGE(1, 1);
  asm volatile("s_waitcnt vmcnt(6)" ::: "memory");
  __builtin_amdgcn_s_barrier();
  __builtin_amdgcn_sched_barrier(0);

  int pc = 0;   // current page
  for (int ks = 0; ks < NKS; ++ks) {
    const int tgt = (pc + 2 >= 3) ? pc - 1 : pc + 2;       // (ks+2)%3
    const int kt  = (ks + 2 < NKS) ? ks + 2 : NKS - 1;     // clamp tail (benign dup)
    STAGE(tgt, kt);

    // ---- frag reads from page pc ----
    bf16x8 a[4], b[4];
    #pragma unroll
    for (int mi = 0; mi < 4; ++mi) {
      const int row = wm * 64 + mi * 16 + c16;
      f32x4 x0 = *(const f32x4*)&A_s[pc][q * 1024 + row * 4];        // k4 = 2q
      f32x4 x1 = *(const f32x4*)&A_s[pc][q * 1024 + 512 + row * 4];  // k4 = 2q+1
      union { u16 s[8]; bf16x8 v8; } pk;
      pk.s[0] = __builtin_bit_cast(u16, (__bf16)x0[0]);
      pk.s[1] = __builtin_bit_cast(u16, (__bf16)x0[1]);
      pk.s[2] = __builtin_bit_cast(u16, (__bf16)x0[2]);
      pk.s[3] = __builtin_bit_cast(u16, (__bf16)x0[3]);
      pk.s[4] = __builtin_bit_cast(u16, (__bf16)x1[0]);
      pk.s[5] = __builtin_bit_cast(u16, (__bf16)x1[1]);
      pk.s[6] = __builtin_bit_cast(u16, (__bf16)x1[2]);
      pk.s[7] = __builtin_bit_cast(u16, (__bf16)x1[3]);
      a[mi] = pk.v8;
    }
    #pragma unroll
    for (int nf = 0; nf < 4; ++nf) {
      const int col = wn * 64 + nf * 16 + c16;
      b[nf] = *(const bf16x8*)&B_s[pc][(q * 128 + col) * 8];
    }

    __builtin_amdgcn_s_setprio(1);
    #pragma unroll
    for (int nf = 0; nf < 4; ++nf)
      #pragma unroll
      for (int mi = 0; mi < 4; ++mi)
        acc[mi][nf] = __builtin_amdgcn_mfma_f32_16x16x32_bf16(
            a[mi], b[nf], acc[mi][nf], 0, 0, 0);
    __builtin_amdgcn_s_setprio(0);

    // counted wait: drains pages for ks+1 (issued last iter); leaves this
    // iter's 6 staging loads (pages ks+2) in flight across the barrier.
    asm volatile("s_waitcnt vmcnt(6)" ::: "memory");
    __builtin_amdgcn_s_barrier();
    __builtin_amdgcn_sched_barrier(0);

    pc = (pc + 1 >= 3) ? 0 : pc + 1;
  }
  #undef STAGE

  // ---- epilogue: rowsum_h v[h]*tanh(acc + u[b][h]) over this slice's 128 cols ----
  float vv[4];
  #pragma unroll
  for (int nf = 0; nf < 4; ++nf)
    vv[nf] = v[n0 + wn * 64 + nf * 16 + c16];

  float rowsum[4][4];
  #pragma unroll
  for (int mi = 0; mi < 4; ++mi)
    #pragma unroll
    for (int r = 0; r < 4; ++r) rowsum[mi][r] = 0.f;

  #pragma unroll
  for (int nf = 0; nf < 4; ++nf) {
    const int h = n0 + wn * 64 + nf * 16 + c16;
    const f32x4 ue = *(const f32x4*)(u_t + (size_t)h * B_DIM + q * 4);
    const f32x4 uo = *(const f32x4*)(u_t + (size_t)h * B_DIM + 16 + q * 4);
    #pragma unroll
    for (int mi = 0; mi < 4; ++mi)
      #pragma unroll
      for (int r = 0; r < 4; ++r) {
        const float uu = (mi & 1) ? uo[r] : ue[r];   // b = (mi&1)*16 + q*4 + r
        rowsum[mi][r] += vv[nf] * fast_tanh(acc[mi][nf][r] + uu);
      }
  }
  #pragma unroll
  for (int mi = 0; mi < 4; ++mi)
    #pragma unroll
    for (int r = 0; r < 4; ++r) {
      float s = rowsum[mi][r];
      s += __shfl_xor(s, 1);
      s += __shfl_xor(s, 2);
      s += __shfl_xor(s, 4);
      s += __shfl_xor(s, 8);
      if (c16 == 0) red_s[wn][wm * 64 + mi * 16 + q * 4 + r] = s;
    }
  __syncthreads();
  if (tid < 128) {
    const float sres = red_s[0][tid] + red_s[1][tid];
    partial[(size_t)ns * M_DIM + (size_t)(tid & 31) * S_DIM + ((m0 + tid) >> 5)] = sres;
  }
}

// softmax over S per batch row b, fused with the 8-slice partial reduction.
// partial layout: [ns][b][s]; out[b][0][s].
__global__ void softmax_kernel(const float* __restrict__ partial, float* __restrict__ out) {
  const int b = blockIdx.x;
  const int t = threadIdx.x;        // 256
  const int lane = t & 63, wid = t >> 6;
  __shared__ float redm[4], reds[4];
  float loc[8];
  float mx = -3.0e38f;
  #pragma unroll
  for (int i = 0; i < 8; ++i) {
    const int s = i * 256 + t;
    float a = 0.f;
    #pragma unroll
    for (int j = 0; j < NSLICE; ++j)
      a += partial[(size_t)j * M_DIM + (size_t)b * S_DIM + s];
    loc[i] = a;
    mx = fmaxf(mx, a);
  }
  #pragma unroll
  for (int off = 1; off < 64; off <<= 1) mx = fmaxf(mx, __shfl_xor(mx, off));
  if (lane == 0) redm[wid] = mx;
  __syncthreads();
  mx = fmaxf(fmaxf(redm[0], redm[1]), fmaxf(redm[2], redm[3]));
  float sum = 0.f;
  #pragma unroll
  for (int i = 0; i < 8; ++i) { loc[i] = __expf(loc[i] - mx); sum += loc[i]; }
  #pragma unroll
  for (int off = 1; off < 64; off <<= 1) sum += __shfl_xor(sum, off);
  if (lane == 0) reds[wid] = sum;
  __syncthreads();
  sum = reds[0] + reds[1] + reds[2] + reds[3];
  float inv = 1.0f / sum;
  #pragma unroll
  for (int i = 0; i < 8; ++i) out[(size_t)b * S_DIM + i * 256 + t] = loc[i] * inv;
}

extern "C" void kernel_launch(void* const* d_in, const int* in_sizes, int n_in,
                              void* d_out, int out_size, void* d_ws, size_t ws_size,
                              hipStream_t stream) {
  const float* hidden = (const float*)d_in[0];
  const float* enc    = (const float*)d_in[1];
  const float* W      = (const float*)d_in[2];
  const float* bias   = (const float*)d_in[3];
  const float* v      = (const float*)d_in[4];
  float* out = (float*)d_out;

  char* ws = (char*)d_ws;
  u16*   W2      = (u16*)ws;                                   // 2 MB
  float* u_t     = (float*)(ws + (2u << 20));                  // 128 KB [H][B]
  float* partial = (float*)(ws + (2304u << 10));               // 2 MB [8][B][S]

  wconv_kernel<<<H_DIM, 256, 0, stream>>>(W, W2);
  uprep_kernel<<<512, 256, 0, stream>>>(hidden, W, bias, u_t);
  gemm_kernel<<<(M_DIM / 128) * NSLICE, 256, 0, stream>>>(enc, W2, u_t, v, partial);
  softmax_kernel<<<B_DIM, 256, 0, stream>>>(partial, out);
}

// Round 11
// 406.598 us; speedup vs baseline: 1.3242x; 1.3242x over previous
//
#include <hip/hip_runtime.h>
#include <hip/hip_bf16.h>

typedef unsigned short u16;
typedef __bf16 bf16x8 __attribute__((ext_vector_type(8)));
typedef float f32x4 __attribute__((ext_vector_type(4)));

#define S_DIM 2048
#define B_DIM 32
#define H_DIM 1024
#define M_DIM (S_DIM * B_DIM)
#define NTILE 16        // K = 1024 in 16 tiles of 64
#define NSLICE 8        // N = 1024 in 8 slices of 128 cols

__device__ __forceinline__ float fast_tanh(float x) {
  // tanh(x) = 1 - 2/(e^{2x}+1); e->inf => 1, e->0 => -1; no NaN
  float e = __expf(2.0f * x);
  return 1.0f - 2.0f * __builtin_amdgcn_rcpf(e + 1.0f);
}

__device__ __forceinline__ void gload_lds16(const void* g, void* l) {
  __builtin_amdgcn_global_load_lds(
      (const __attribute__((address_space(1))) unsigned int*)g,
      (__attribute__((address_space(3))) unsigned int*)l,
      16, 0, 0);
}

__device__ __forceinline__ uint4 pack8(float4 fa, float4 fb) {
  union { u16 s[8]; uint4 v; } pk;
  pk.s[0] = __builtin_bit_cast(u16, (__bf16)fa.x);
  pk.s[1] = __builtin_bit_cast(u16, (__bf16)fa.y);
  pk.s[2] = __builtin_bit_cast(u16, (__bf16)fa.z);
  pk.s[3] = __builtin_bit_cast(u16, (__bf16)fa.w);
  pk.s[4] = __builtin_bit_cast(u16, (__bf16)fb.x);
  pk.s[5] = __builtin_bit_cast(u16, (__bf16)fb.y);
  pk.s[6] = __builtin_bit_cast(u16, (__bf16)fb.z);
  pk.s[7] = __builtin_bit_cast(u16, (__bf16)fb.w);
  return pk.v;
}

// enc f32 (256MB) -> bf16 (128MB). 1024 blocks x 256 thr x 256 elems.
__global__ void cvt_kernel(const float* __restrict__ in, u16* __restrict__ out) {
  const size_t base = (size_t)blockIdx.x * 65536 + (size_t)threadIdx.x * 8;
  #pragma unroll 4
  for (int i = 0; i < 32; ++i) {
    const size_t off = base + (size_t)i * 2048;
    float4 f0 = *(const float4*)(in + off);
    float4 f1 = *(const float4*)(in + off + 4);
    *(uint4*)(out + off) = pack8(f0, f1);
  }
}

// Convert W_attn[:, H:2H] (f32, row stride 2H) -> W2 bf16 [H][H] row-major
__global__ void wconv_kernel(const float* __restrict__ W, u16* __restrict__ W2) {
  const int h = blockIdx.x;
  const int t = threadIdx.x;
  float4 w4 = *(const float4*)(W + (size_t)h * (2 * H_DIM) + H_DIM + t * 4);
  union { u16 s[4]; uint2 v; } pk;
  pk.s[0] = __builtin_bit_cast(u16, (__bf16)w4.x);
  pk.s[1] = __builtin_bit_cast(u16, (__bf16)w4.y);
  pk.s[2] = __builtin_bit_cast(u16, (__bf16)w4.z);
  pk.s[3] = __builtin_bit_cast(u16, (__bf16)w4.w);
  *(uint2*)(W2 + (size_t)h * H_DIM + t * 4) = pk.v;
}

// u_t[h][b] = dot(hidden[b,:], W_attn[h, 0:H]) + b_attn[h]   (fp32, transposed)
__global__ void uprep_kernel(const float* __restrict__ hidden, const float* __restrict__ W,
                             const float* __restrict__ bias, float* __restrict__ u_t) {
  int t = blockIdx.x * 256 + threadIdx.x;   // 0..131071
  int h = t >> 7;
  int b = (t >> 2) & 31;
  int kq = t & 3;
  const float4* hv = (const float4*)(hidden + (size_t)b * H_DIM) + kq * 64;
  const float4* wv = (const float4*)(W + (size_t)h * (2 * H_DIM)) + kq * 64;
  float acc = 0.f;
  #pragma unroll 4
  for (int i = 0; i < 64; ++i) {
    float4 a = hv[i], w = wv[i];
    acc += a.x * w.x + a.y * w.y + a.z * w.z + a.w * w.w;
  }
  acc += __shfl_xor(acc, 1);
  acc += __shfl_xor(acc, 2);
  if (kq == 0) u_t[(size_t)h * B_DIM + b] = acc + bias[h];
}

// Fused GEMM + tanh + v-dot. 128x128 tile, BK=64 (32 MFMA/wave per sync-wall,
// 2x R7/R10), 256 thr / 4 waves (2x2), wave 64x64, acc[4][4] = 64 AGPR.
// BF16A=1: both operands staged pure global_load_lds from pre-converted
// enc_bf16; LDS 65KB -> 2 blocks/CU (cross-block drain overlap, m114).
// BF16A=0 fallback (small ws): A staged f32 via global_load_lds, cvt at
// frag-read; LDS 97KB -> 1 block/CU.
// kq-major pages (slot = kq*128 + row; 16B/slot): linear gload dest,
// 16-lane-contiguous ds reads, measured 0 conflicts (R4/R7/R10).
// XCD-bijective swizzle: 8 n-siblings of an m-panel share an XCD (R6).
template<int BF16A>
__global__ __launch_bounds__(256, 2)
void gemm_kernel(const float* __restrict__ encf, const u16* __restrict__ encb,
                 const u16* __restrict__ W2, const float* __restrict__ u_t,
                 const float* __restrict__ v, float* __restrict__ partial) {
  __shared__ char A_pg[2][BF16A ? 16384 : 32768];
  __shared__ char B_pg[2][16384];
  __shared__ float red_s[2][128];

  const int tid  = threadIdx.x;
  const int lane = tid & 63;
  const int w    = tid >> 6;    // 0..3
  const int wm   = w >> 1;      // 0..1
  const int wn   = w & 1;       // 0..1
  const int q    = lane >> 4;   // 0..3
  const int c16  = lane & 15;

  // XCD-bijective decode (4096 blocks): xcd = blockIdx%8; siblings share it.
  const int bidx = blockIdx.x;
  const int ns   = (bidx >> 3) & 7;
  const int mt   = (bidx & 7) + 8 * (bidx >> 6);
  const int m0   = mt * 128;
  const int n0   = ns * 128;

  f32x4 acc[4][4];
  #pragma unroll
  for (int mi = 0; mi < 4; ++mi)
    #pragma unroll
    for (int nf = 0; nf < 4; ++nf) {
      f32x4 z = {0.f, 0.f, 0.f, 0.f};
      acc[mi][nf] = z;
    }

  // stage K-tile kt into page pg
  #define STAGE(pg, kt)                                                       \
    {                                                                         \
      _Pragma("unroll")                                                       \
      for (int j = 0; j < 4; ++j) {                                           \
        const int slot = j * 256 + tid;                                       \
        const int kq = slot >> 7, col = slot & 127;                           \
        gload_lds16(W2 + (size_t)(n0 + col) * H_DIM + (kt) * 64 + kq * 8,     \
                    &B_pg[pg][slot * 16]);                                    \
      }                                                                       \
      if (BF16A) {                                                            \
        _Pragma("unroll")                                                     \
        for (int j = 0; j < 4; ++j) {                                         \
          const int slot = j * 256 + tid;                                     \
          const int kq = slot >> 7, row = slot & 127;                         \
          gload_lds16(encb + (size_t)(m0 + row) * H_DIM + (kt) * 64 + kq * 8, \
                      &A_pg[pg][slot * 16]);                                  \
        }                                                                     \
      } else {                                                                \
        _Pragma("unroll")                                                     \
        for (int j = 0; j < 8; ++j) {                                         \
          const int slot = j * 256 + tid;                                     \
          const int k4 = slot >> 7, row = slot & 127;                         \
          gload_lds16(encf + (size_t)(m0 + row) * H_DIM + (kt) * 64 + k4 * 4, \
                      &A_pg[pg][slot * 16]);                                  \
        }                                                                     \
      }                                                                       \
    }

  STAGE(0, 0);
  __syncthreads();

  for (int t = 0; t < NTILE; ++t) {
    const int pg = t & 1;
    if (t + 1 < NTILE) STAGE(pg ^ 1, t + 1);

    #pragma unroll
    for (int kk = 0; kk < 2; ++kk) {
      bf16x8 a[4], b[4];
      #pragma unroll
      for (int mi = 0; mi < 4; ++mi) {
        const int row = wm * 64 + mi * 16 + c16;
        if (BF16A) {
          a[mi] = *(const bf16x8*)&A_pg[pg][((kk * 4 + q) * 128 + row) * 16];
        } else {
          f32x4 x0 = *(const f32x4*)&A_pg[pg][(((kk * 8 + q * 2)    ) * 128 + row) * 16];
          f32x4 x1 = *(const f32x4*)&A_pg[pg][(((kk * 8 + q * 2) + 1) * 128 + row) * 16];
          union { u16 s[8]; bf16x8 v8; } pk;
          pk.s[0] = __builtin_bit_cast(u16, (__bf16)x0[0]);
          pk.s[1] = __builtin_bit_cast(u16, (__bf16)x0[1]);
          pk.s[2] = __builtin_bit_cast(u16, (__bf16)x0[2]);
          pk.s[3] = __builtin_bit_cast(u16, (__bf16)x0[3]);
          pk.s[4] = __builtin_bit_cast(u16, (__bf16)x1[0]);
          pk.s[5] = __builtin_bit_cast(u16, (__bf16)x1[1]);
          pk.s[6] = __builtin_bit_cast(u16, (__bf16)x1[2]);
          pk.s[7] = __builtin_bit_cast(u16, (__bf16)x1[3]);
          a[mi] = pk.v8;
        }
      }
      #pragma unroll
      for (int nf = 0; nf < 4; ++nf) {
        const int col = wn * 64 + nf * 16 + c16;
        b[nf] = *(const bf16x8*)&B_pg[pg][((kk * 4 + q) * 128 + col) * 16];
      }
      __builtin_amdgcn_s_setprio(1);
      #pragma unroll
      for (int nf = 0; nf < 4; ++nf)
        #pragma unroll
        for (int mi = 0; mi < 4; ++mi)
          acc[mi][nf] = __builtin_amdgcn_mfma_f32_16x16x32_bf16(
              a[mi], b[nf], acc[mi][nf], 0, 0, 0);
      __builtin_amdgcn_s_setprio(0);
    }
    __syncthreads();
  }
  #undef STAGE

  // ---- epilogue: rowsum_h v[h]*tanh(acc + u[b][h]) over this slice's 128 cols ----
  float vv[4];
  #pragma unroll
  for (int nf = 0; nf < 4; ++nf)
    vv[nf] = v[n0 + wn * 64 + nf * 16 + c16];

  float rowsum[4][4];
  #pragma unroll
  for (int mi = 0; mi < 4; ++mi)
    #pragma unroll
    for (int r = 0; r < 4; ++r) rowsum[mi][r] = 0.f;

  #pragma unroll
  for (int nf = 0; nf < 4; ++nf) {
    const int h = n0 + wn * 64 + nf * 16 + c16;
    const f32x4 ue = *(const f32x4*)(u_t + (size_t)h * B_DIM + q * 4);
    const f32x4 uo = *(const f32x4*)(u_t + (size_t)h * B_DIM + 16 + q * 4);
    #pragma unroll
    for (int mi = 0; mi < 4; ++mi)
      #pragma unroll
      for (int r = 0; r < 4; ++r) {
        const float uu = (mi & 1) ? uo[r] : ue[r];   // b = (mi&1)*16 + q*4 + r
        rowsum[mi][r] += vv[nf] * fast_tanh(acc[mi][nf][r] + uu);
      }
  }
  #pragma unroll
  for (int mi = 0; mi < 4; ++mi)
    #pragma unroll
    for (int r = 0; r < 4; ++r) {
      float s = rowsum[mi][r];
      s += __shfl_xor(s, 1);
      s += __shfl_xor(s, 2);
      s += __shfl_xor(s, 4);
      s += __shfl_xor(s, 8);
      if (c16 == 0) red_s[wn][wm * 64 + mi * 16 + q * 4 + r] = s;
    }
  __syncthreads();
  if (tid < 128) {
    const float sres = red_s[0][tid] + red_s[1][tid];
    partial[(size_t)ns * M_DIM + (size_t)(tid & 31) * S_DIM + ((m0 + tid) >> 5)] = sres;
  }
}

// softmax over S per batch row b, fused with the 8-slice partial reduction.
// partial layout: [ns][b][s]; out[b][0][s].
__global__ void softmax_kernel(const float* __restrict__ partial, float* __restrict__ out) {
  const int b = blockIdx.x;
  const int t = threadIdx.x;        // 256
  const int lane = t & 63, wid = t >> 6;
  __shared__ float redm[4], reds[4];
  float loc[8];
  float mx = -3.0e38f;
  #pragma unroll
  for (int i = 0; i < 8; ++i) {
    const int s = i * 256 + t;
    float a = 0.f;
    #pragma unroll
    for (int j = 0; j < NSLICE; ++j)
      a += partial[(size_t)j * M_DIM + (size_t)b * S_DIM + s];
    loc[i] = a;
    mx = fmaxf(mx, a);
  }
  #pragma unroll
  for (int off = 1; off < 64; off <<= 1) mx = fmaxf(mx, __shfl_xor(mx, off));
  if (lane == 0) redm[wid] = mx;
  __syncthreads();
  mx = fmaxf(fmaxf(redm[0], redm[1]), fmaxf(redm[2], redm[3]));
  float sum = 0.f;
  #pragma unroll
  for (int i = 0; i < 8; ++i) { loc[i] = __expf(loc[i] - mx); sum += loc[i]; }
  #pragma unroll
  for (int off = 1; off < 64; off <<= 1) sum += __shfl_xor(sum, off);
  if (lane == 0) reds[wid] = sum;
  __syncthreads();
  sum = reds[0] + reds[1] + reds[2] + reds[3];
  float inv = 1.0f / sum;
  #pragma unroll
  for (int i = 0; i < 8; ++i) out[(size_t)b * S_DIM + i * 256 + t] = loc[i] * inv;
}

extern "C" void kernel_launch(void* const* d_in, const int* in_sizes, int n_in,
                              void* d_out, int out_size, void* d_ws, size_t ws_size,
                              hipStream_t stream) {
  const float* hidden = (const float*)d_in[0];
  const float* enc    = (const float*)d_in[1];
  const float* W      = (const float*)d_in[2];
  const float* bias   = (const float*)d_in[3];
  const float* v      = (const float*)d_in[4];
  float* out = (float*)d_out;

  char* ws = (char*)d_ws;
  u16*   W2      = (u16*)ws;                                   // 2 MB @ 0
  float* u_t     = (float*)(ws + (2048u << 10));               // 128 KB @ 2MB
  float* partial = (float*)(ws + (2304u << 10));               // 2 MB @ 2.25MB
  const size_t ENC16_OFF = (size_t)4352 << 10;                 // @ 4.25MB
  u16*   encb    = (u16*)(ws + ENC16_OFF);                     // 128 MB
  const size_t need = ENC16_OFF + (size_t)M_DIM * H_DIM * 2;

  wconv_kernel<<<H_DIM, 256, 0, stream>>>(W, W2);
  uprep_kernel<<<512, 256, 0, stream>>>(hidden, W, bias, u_t);
  if (ws_size >= need) {
    cvt_kernel<<<1024, 256, 0, stream>>>(enc, encb);
    gemm_kernel<1><<<4096, 256, 0, stream>>>(enc, encb, W2, u_t, v, partial);
  } else {
    gemm_kernel<0><<<4096, 256, 0, stream>>>(enc, encb, W2, u_t, v, partial);
  }
  softmax_kernel<<<B_DIM, 256, 0, stream>>>(partial, out);
}